// Round 2
// baseline (3361.844 us; speedup 1.0000x reference)
//
#include <hip/hip_runtime.h>
#include <math.h>

// AxileAttention: out = softmax((X@Wq + bq) * (X@Wk + bk), axis=-1) * (X@Wv + bv)
// per (b,c) channel, right-matmul over W axis. All fp32.
// B=8 C=64 H=256 W=256.
//
// Design: block = 256 thr = 4 waves, owns (b, c, 32 rows).
//   - wave w holds its 8 X rows entirely in registers (lane j holds cols 4j..4j+3)
//   - per-k broadcast of x[r][k] via v_readlane -> SGPR (VALU pipe, no LDS)
//   - weights staged in LDS per BK=16 K-tile (3*16*256*4 = 48 KB -> 3 blocks/CU)
//   - softmax is an intra-wave (64-lane) reduction; fully coalesced float4 I/O.

#define Bn 8
#define Cn 64
#define Hn 256
#define Wn 256
#define BM 32
#define BK 16
#define NT 256

__device__ __forceinline__ float wave_reduce_max(float v) {
#pragma unroll
    for (int off = 32; off > 0; off >>= 1)
        v = fmaxf(v, __shfl_xor(v, off, 64));
    return v;
}

__device__ __forceinline__ float wave_reduce_sum(float v) {
#pragma unroll
    for (int off = 32; off > 0; off >>= 1)
        v += __shfl_xor(v, off, 64);
    return v;
}

__device__ __forceinline__ void fma4(float4& acc, float s, const float4& wv) {
    acc.x = fmaf(s, wv.x, acc.x);
    acc.y = fmaf(s, wv.y, acc.y);
    acc.z = fmaf(s, wv.z, acc.z);
    acc.w = fmaf(s, wv.w, acc.w);
}

__global__ __launch_bounds__(NT, 3) void axile_attn_fp32(
    const float* __restrict__ x,
    const float* __restrict__ wq,
    const float* __restrict__ wk,
    const float* __restrict__ wv,
    const float* __restrict__ bq,
    const float* __restrict__ bk,
    const float* __restrict__ bv,
    float* __restrict__ out)
{
    __shared__ float Ws[3][BK][Wn];  // 48 KB

    const int tid  = threadIdx.x;
    const int wave = tid >> 6;
    const int lane = tid & 63;

    // XCD-aware swizzle: 4096 blocks = 8 xcd * 512; each XCD owns 8 channels
    // so one channel's 768 KB weight set stays in one XCD's 4 MB L2.
    const int blk   = blockIdx.x;
    const int xcd   = blk & 7;
    const int local = blk >> 3;          // [0,512)
    const int c   = (xcd << 3) | (local >> 6);  // 8 channels per xcd
    const int rem = local & 63;
    const int b   = rem >> 3;
    const int t   = rem & 7;
    const int h0  = t * BM;
    const int r0  = wave * 8;            // this wave's first row within the tile

    const float* xp  = x  + (((size_t)(b * Cn + c)) * Hn + (h0 + r0)) * Wn + lane * 4;
    const float* wqp = wq + (size_t)c * Wn * Wn;
    const float* wkp = wk + (size_t)c * Wn * Wn;
    const float* wvp = wv + (size_t)c * Wn * Wn;

    // X rows live in registers for the whole kernel: 8 rows x 4 cols/lane.
    float4 xr[8];
#pragma unroll
    for (int r = 0; r < 8; ++r)
        xr[r] = *(const float4*)(xp + r * Wn);

    float4 aq[8], ak[8], av[8];
#pragma unroll
    for (int r = 0; r < 8; ++r) {
        aq[r] = make_float4(0.f, 0.f, 0.f, 0.f);
        ak[r] = make_float4(0.f, 0.f, 0.f, 0.f);
        av[r] = make_float4(0.f, 0.f, 0.f, 0.f);
    }

    for (int kt = 0; kt < Wn / BK; ++kt) {
        const int k0 = kt * BK;
        __syncthreads();  // all waves done reading previous K-tile of Ws
#pragma unroll
        for (int j = 0; j < 4; ++j) {
            const int f = tid + j * NT;  // float4 index in [0,1024), coalesced
            const float4 lq = *(const float4*)(wqp + (size_t)k0 * Wn + (size_t)f * 4);
            const float4 lk = *(const float4*)(wkp + (size_t)k0 * Wn + (size_t)f * 4);
            const float4 lv = *(const float4*)(wvp + (size_t)k0 * Wn + (size_t)f * 4);
            ((float4*)&Ws[0][0][0])[f] = lq;
            ((float4*)&Ws[1][0][0])[f] = lk;
            ((float4*)&Ws[2][0][0])[f] = lv;
        }
        __syncthreads();

#pragma unroll
        for (int kk = 0; kk < BK; ++kk) {
            const int srclane = (k0 + kk) >> 2;  // wave-uniform
            // broadcast x[r][k0+kk] to all lanes via readlane -> SGPR
            float sx[8];
#pragma unroll
            for (int r = 0; r < 8; ++r) {
                const int comp = kk & 3;  // compile-time after unroll
                float xv = (comp == 0) ? xr[r].x
                         : (comp == 1) ? xr[r].y
                         : (comp == 2) ? xr[r].z
                                       : xr[r].w;
                sx[r] = __int_as_float(
                    __builtin_amdgcn_readlane(__float_as_int(xv), srclane));
            }
            const float4 wq4 = *(const float4*)&Ws[0][kk][lane * 4];
            const float4 wk4 = *(const float4*)&Ws[1][kk][lane * 4];
            const float4 wv4 = *(const float4*)&Ws[2][kk][lane * 4];
#pragma unroll
            for (int r = 0; r < 8; ++r) {
                fma4(aq[r], sx[r], wq4);
                fma4(ak[r], sx[r], wk4);
                fma4(av[r], sx[r], wv4);
            }
        }
    }

    // Epilogue: bias add, s = q*k, row softmax (intra-wave), * v, store.
    const size_t browbase = ((size_t)c * Hn + (size_t)(h0 + r0)) * Wn + lane * 4;
    const float* bqp = bq + browbase;
    const float* bkp = bk + browbase;
    const float* bvp = bv + browbase;
    float* op = out + (((size_t)(b * Cn + c)) * Hn + (size_t)(h0 + r0)) * Wn + lane * 4;

#pragma unroll
    for (int r = 0; r < 8; ++r) {
        const float4 bq4 = *(const float4*)(bqp + r * Wn);
        const float4 bk4 = *(const float4*)(bkp + r * Wn);
        const float4 bv4 = *(const float4*)(bvp + r * Wn);

        float4 q4 = make_float4(aq[r].x + bq4.x, aq[r].y + bq4.y,
                                aq[r].z + bq4.z, aq[r].w + bq4.w);
        float4 k4 = make_float4(ak[r].x + bk4.x, ak[r].y + bk4.y,
                                ak[r].z + bk4.z, ak[r].w + bk4.w);
        float4 v4 = make_float4(av[r].x + bv4.x, av[r].y + bv4.y,
                                av[r].z + bv4.z, av[r].w + bv4.w);

        float4 s4 = make_float4(q4.x * k4.x, q4.y * k4.y, q4.z * k4.z, q4.w * k4.w);

        float mx = fmaxf(fmaxf(s4.x, s4.y), fmaxf(s4.z, s4.w));
        mx = wave_reduce_max(mx);

        float4 e4 = make_float4(expf(s4.x - mx), expf(s4.y - mx),
                                expf(s4.z - mx), expf(s4.w - mx));
        float sm = e4.x + e4.y + e4.z + e4.w;
        sm = wave_reduce_sum(sm);
        const float inv = 1.0f / sm;

        float4 o4 = make_float4(e4.x * v4.x * inv, e4.y * v4.y * inv,
                                e4.z * v4.z * inv, e4.w * v4.w * inv);
        *(float4*)(op + r * Wn) = o4;
    }
}

extern "C" void kernel_launch(void* const* d_in, const int* in_sizes, int n_in,
                              void* d_out, int out_size, void* d_ws, size_t ws_size,
                              hipStream_t stream) {
    (void)in_sizes; (void)n_in; (void)out_size; (void)d_ws; (void)ws_size;
    const float* x  = (const float*)d_in[0];
    const float* wq = (const float*)d_in[1];
    const float* wk = (const float*)d_in[2];
    const float* wv = (const float*)d_in[3];
    const float* bq = (const float*)d_in[4];
    const float* bk = (const float*)d_in[5];
    const float* bv = (const float*)d_in[6];
    float* out = (float*)d_out;

    dim3 grid(Bn * Cn * (Hn / BM));  // 4096
    dim3 block(NT);
    hipLaunchKernelGGL(axile_attn_fp32, grid, block, 0, stream,
                       x, wq, wk, wv, bq, bk, bv, out);
}

// Round 3
// 862.568 us; speedup vs baseline: 3.8975x; 3.8975x over previous
//
#include <hip/hip_runtime.h>
#include <math.h>

// AxileAttention: out = softmax((X@Wq + bq) * (X@Wk + bk), axis=-1) * (X@Wv + bv)
// per (b,c) channel, right-matmul over W axis. All fp32.
// B=8 C=64 H=256 W=256.
//
// Round 3: fix Round-2's register spill (VGPR_Count=84 < ~160 live ->
// 7.9 GB scratch writes). __launch_bounds__(256,2) gives the allocator a
// 256-VGPR budget; LDS (48 KB) still caps occupancy at 3 blocks/CU.
// Also dropped the XCD channel-pinning (6 MB weights per 4 MB L2 = thrash);
// natural ordering keeps ~1-2 active channels per XCD L2.

#define Bn 8
#define Cn 64
#define Hn 256
#define Wn 256
#define BM 32
#define BK 16
#define NT 256

__device__ __forceinline__ float wave_reduce_max(float v) {
#pragma unroll
    for (int off = 32; off > 0; off >>= 1)
        v = fmaxf(v, __shfl_xor(v, off, 64));
    return v;
}

__device__ __forceinline__ float wave_reduce_sum(float v) {
#pragma unroll
    for (int off = 32; off > 0; off >>= 1)
        v += __shfl_xor(v, off, 64);
    return v;
}

__device__ __forceinline__ void fma4(float4& acc, float s, const float4& wv) {
    acc.x = fmaf(s, wv.x, acc.x);
    acc.y = fmaf(s, wv.y, acc.y);
    acc.z = fmaf(s, wv.z, acc.z);
    acc.w = fmaf(s, wv.w, acc.w);
}

__global__ __launch_bounds__(NT, 2) void axile_attn_fp32(
    const float* __restrict__ x,
    const float* __restrict__ wq,
    const float* __restrict__ wk,
    const float* __restrict__ wv,
    const float* __restrict__ bq,
    const float* __restrict__ bk,
    const float* __restrict__ bv,
    float* __restrict__ out)
{
    __shared__ float Ws[3][BK][Wn];  // 48 KB

    const int tid  = threadIdx.x;
    const int wave = tid >> 6;
    const int lane = tid & 63;

    // Natural mapping: blk = c*64 + b*8 + t. Consecutive blocks share a
    // channel and are spread round-robin over XCDs, so each XCD's L2 holds
    // only the ~2 channels currently in flight (~1.5 MB) -> weight reuse.
    const int blk = blockIdx.x;
    const int c   = blk >> 6;
    const int b   = (blk >> 3) & 7;
    const int t   = blk & 7;
    const int h0  = t * BM;
    const int r0  = wave * 8;            // this wave's first row within the tile

    const float* xp  = x  + (((size_t)(b * Cn + c)) * Hn + (h0 + r0)) * Wn + lane * 4;
    const float* wqp = wq + (size_t)c * Wn * Wn;
    const float* wkp = wk + (size_t)c * Wn * Wn;
    const float* wvp = wv + (size_t)c * Wn * Wn;

    // X rows live in registers for the whole kernel: 8 rows x 4 cols/lane.
    float4 xr[8];
#pragma unroll
    for (int r = 0; r < 8; ++r)
        xr[r] = *(const float4*)(xp + r * Wn);

    float4 aq[8], ak[8], av[8];
#pragma unroll
    for (int r = 0; r < 8; ++r) {
        aq[r] = make_float4(0.f, 0.f, 0.f, 0.f);
        ak[r] = make_float4(0.f, 0.f, 0.f, 0.f);
        av[r] = make_float4(0.f, 0.f, 0.f, 0.f);
    }

    for (int kt = 0; kt < Wn / BK; ++kt) {
        const int k0 = kt * BK;
        __syncthreads();  // all waves done reading previous K-tile of Ws
#pragma unroll
        for (int j = 0; j < 4; ++j) {
            const int f = tid + j * NT;  // float4 index in [0,1024), coalesced
            const float4 lq = *(const float4*)(wqp + (size_t)k0 * Wn + (size_t)f * 4);
            const float4 lk = *(const float4*)(wkp + (size_t)k0 * Wn + (size_t)f * 4);
            const float4 lv = *(const float4*)(wvp + (size_t)k0 * Wn + (size_t)f * 4);
            ((float4*)&Ws[0][0][0])[f] = lq;
            ((float4*)&Ws[1][0][0])[f] = lk;
            ((float4*)&Ws[2][0][0])[f] = lv;
        }
        __syncthreads();

#pragma unroll
        for (int kk = 0; kk < BK; ++kk) {
            const int srclane = (k0 + kk) >> 2;  // wave-uniform
            // broadcast x[r][k0+kk] to all lanes via readlane -> SGPR
            float sx[8];
#pragma unroll
            for (int r = 0; r < 8; ++r) {
                const int comp = kk & 3;  // compile-time after unroll
                float xv = (comp == 0) ? xr[r].x
                         : (comp == 1) ? xr[r].y
                         : (comp == 2) ? xr[r].z
                                       : xr[r].w;
                sx[r] = __int_as_float(
                    __builtin_amdgcn_readlane(__float_as_int(xv), srclane));
            }
            const float4 wq4 = *(const float4*)&Ws[0][kk][lane * 4];
            const float4 wk4 = *(const float4*)&Ws[1][kk][lane * 4];
            const float4 wv4 = *(const float4*)&Ws[2][kk][lane * 4];
#pragma unroll
            for (int r = 0; r < 8; ++r) {
                fma4(aq[r], sx[r], wq4);
                fma4(ak[r], sx[r], wk4);
                fma4(av[r], sx[r], wv4);
            }
        }
    }

    // Epilogue: bias add, s = q*k, row softmax (intra-wave), * v, store.
    const size_t browbase = ((size_t)c * Hn + (size_t)(h0 + r0)) * Wn + lane * 4;
    const float* bqp = bq + browbase;
    const float* bkp = bk + browbase;
    const float* bvp = bv + browbase;
    float* op = out + (((size_t)(b * Cn + c)) * Hn + (size_t)(h0 + r0)) * Wn + lane * 4;

#pragma unroll
    for (int r = 0; r < 8; ++r) {
        const float4 bq4 = *(const float4*)(bqp + r * Wn);
        const float4 bk4 = *(const float4*)(bkp + r * Wn);
        const float4 bv4 = *(const float4*)(bvp + r * Wn);

        float4 q4 = make_float4(aq[r].x + bq4.x, aq[r].y + bq4.y,
                                aq[r].z + bq4.z, aq[r].w + bq4.w);
        float4 k4 = make_float4(ak[r].x + bk4.x, ak[r].y + bk4.y,
                                ak[r].z + bk4.z, ak[r].w + bk4.w);
        float4 v4 = make_float4(av[r].x + bv4.x, av[r].y + bv4.y,
                                av[r].z + bv4.z, av[r].w + bv4.w);

        float4 s4 = make_float4(q4.x * k4.x, q4.y * k4.y, q4.z * k4.z, q4.w * k4.w);

        float mx = fmaxf(fmaxf(s4.x, s4.y), fmaxf(s4.z, s4.w));
        mx = wave_reduce_max(mx);

        float4 e4 = make_float4(expf(s4.x - mx), expf(s4.y - mx),
                                expf(s4.z - mx), expf(s4.w - mx));
        float sm = e4.x + e4.y + e4.z + e4.w;
        sm = wave_reduce_sum(sm);
        const float inv = 1.0f / sm;

        float4 o4 = make_float4(e4.x * v4.x * inv, e4.y * v4.y * inv,
                                e4.z * v4.z * inv, e4.w * v4.w * inv);
        *(float4*)(op + r * Wn) = o4;
    }
}

extern "C" void kernel_launch(void* const* d_in, const int* in_sizes, int n_in,
                              void* d_out, int out_size, void* d_ws, size_t ws_size,
                              hipStream_t stream) {
    (void)in_sizes; (void)n_in; (void)out_size; (void)d_ws; (void)ws_size;
    const float* x  = (const float*)d_in[0];
    const float* wq = (const float*)d_in[1];
    const float* wk = (const float*)d_in[2];
    const float* wv = (const float*)d_in[3];
    const float* bq = (const float*)d_in[4];
    const float* bk = (const float*)d_in[5];
    const float* bv = (const float*)d_in[6];
    float* out = (float*)d_out;

    dim3 grid(Bn * Cn * (Hn / BM));  // 4096
    dim3 block(NT);
    hipLaunchKernelGGL(axile_attn_fp32, grid, block, 0, stream,
                       x, wq, wk, wv, bq, bk, bv, out);
}